// Round 5
// baseline (97.456 us; speedup 1.0000x reference)
//
#include <hip/hip_runtime.h>
#include <math.h>

#define N_TOTAL 8192
#define BHALF   4096
#define KDIM    128
#define TILE    256
#define NT      32          // 8192 / 256 tile grid
#define NTRI    528         // 32*33/2 triangular tiles
#define NBLK    256         // 1 block per CU (LDS-forced)
#define NSLOT   32          // Tpart slots

typedef __bf16 bf16x8 __attribute__((ext_vector_type(8)));
typedef __bf16 bf16x2 __attribute__((ext_vector_type(2)));
typedef float  f32x4  __attribute__((ext_vector_type(4)));

// async global->LDS, 16B per lane; LDS dest must be lane-contiguous.
#define GLOAD_LDS16(GSRC, LDST)                                                \
    __builtin_amdgcn_global_load_lds(                                          \
        (const __attribute__((address_space(1))) void*)(GSRC),                 \
        (__attribute__((address_space(3))) void*)(LDST), 16, 0, 0)

// ---------------------------------------------------------------------------
// Kernel A (fused prep+pos): one wave per pair (i, i+BHALF).
//  - fp32 sq-norms (exact), bf16 copy, pos-pair partials to posPart,
//  - block 0 zeroes out[0].
// ---------------------------------------------------------------------------
__global__ __launch_bounds__(256) void k_prep_pos(const float* __restrict__ F,
                                                  __bf16* __restrict__ Fbf,
                                                  float* __restrict__ sq,
                                                  float* __restrict__ posPart,
                                                  float* __restrict__ out) {
    int t = threadIdx.x;
    int w = t >> 6, l = t & 63;
    int p = blockIdx.x * 4 + w;          // pair index 0..4095
    const float2* r1 = (const float2*)(F + (size_t)p * KDIM);
    const float2* r2 = (const float2*)(F + (size_t)(p + BHALF) * KDIM);
    float2 a = r1[l];
    float2 c = r2[l];

    float s1 = fmaf(a.x, a.x, a.y * a.y);
    float s2 = fmaf(c.x, c.x, c.y * c.y);
    float dp = fmaf(a.x, c.x, a.y * c.y);
#pragma unroll
    for (int off = 32; off > 0; off >>= 1) {
        s1 += __shfl_down(s1, off);
        s2 += __shfl_down(s2, off);
        dp += __shfl_down(dp, off);
    }

    bf16x2 pa, pc;
    pa[0] = (__bf16)a.x; pa[1] = (__bf16)a.y;
    pc[0] = (__bf16)c.x; pc[1] = (__bf16)c.y;
    ((bf16x2*)(Fbf + (size_t)p * KDIM))[l] = pa;
    ((bf16x2*)(Fbf + (size_t)(p + BHALF) * KDIM))[l] = pc;

    __shared__ float posRed[4];
    if (l == 0) {
        sq[p] = s1;
        sq[p + BHALF] = s2;
        float d2 = fmaxf(s1 + s2 - 2.0f * dp, 0.0f);
        posRed[w] = logf(1.0f + d2);
    }
    __syncthreads();
    if (t == 0) {
        posPart[blockIdx.x] = posRed[0] + posRed[1] + posRed[2] + posRed[3];
        if (blockIdx.x == 0) out[0] = 0.0f;
    }
}

// ---------------------------------------------------------------------------
// Kernel B: MFMA pairwise Cauchy row/col sums, 256x256 tiles, 1 block/CU.
// 8 waves (4x2 grid), each owns 64x128 output (acc[4][8] f32x4 = 128 VGPR):
// 12 ds_read_b128 per K-step for 32 MFMAs — 2x less DS traffic per element
// than the 128^2 version. LDS: As 64K + Bs 64K + accumulators 6K = 134 KB.
// Two barriers per tile; next tile's global_load_lds issued under the
// epilogue; A-panel reuse; diag tiles alias the A panel; XOR-swizzled
// staging; deterministic Tpart scatter over 32 slots (no atomics).
// 240 blocks own 2 tiles, 16 own 3 (cheap diag-dense bottom rows).
// ---------------------------------------------------------------------------
__global__ __launch_bounds__(512, 2) void k_pairwise(
        const __bf16* __restrict__ Fbf,
        const float* __restrict__ sq,
        float* __restrict__ Tpart) {
    __shared__ __align__(16) __bf16 As[TILE * KDIM];   // 64 KB
    __shared__ __align__(16) __bf16 Bs[TILE * KDIM];   // 64 KB
    __shared__ float rowAcc[TILE][2];
    __shared__ float colAcc[TILE][4];

    int t = threadIdx.x;
    int w = t >> 6;              // wave 0..7
    int l = t & 63;
    int wr = w >> 1, wc = w & 1; // 4x2 wave grid: own 64 rows x 128 cols
    int low = l & 15, kb = l >> 4;

    // chunk map: blocks 0..239 -> 2 tiles (top), 240..255 -> 3 tiles (bottom)
    int bid = blockIdx.x;
    int start, cnt;
    if (bid < 240) { start = bid * 2;                cnt = 2; }
    else           { start = 480 + (bid - 240) * 3;  cnt = 3; }

    // decode start -> (ti, tj) on the 32x32 upper triangle, row-major
    int ti = 0;
    while ((ti + 1) * (65 - (ti + 1)) / 2 <= start) ++ti;
    int tj = ti + (start - ti * (65 - ti) / 2);

    // stage one 256x128 bf16 tile (4096 16B granules, XOR-swizzled source)
    auto stage = [&](const __bf16* src, __bf16* dst) {
#pragma unroll
        for (int it = 0; it < 8; ++it) {
            int f = it * 512 + t;            // granule slot 0..4095
            int row = f >> 4;
            int sg = f & 15;
            int g = sg ^ (row & 15);         // global granule landing here
            GLOAD_LDS16(src + row * KDIM + g * 8, dst + (size_t)f * 8);
        }
    };

    // prologue: stage first tile
    stage(Fbf + (size_t)ti * TILE * KDIM, As);
    if (ti != tj) stage(Fbf + (size_t)tj * TILE * KDIM, Bs);
    __syncthreads();

#pragma unroll 1
    for (int n = 0; n < cnt; ++n) {
        int I = ti * TILE, J = tj * TILE;
        bool diag = (ti == tj);

        // ---- MFMA K-loop: 4 steps of K=32, 4x8 fragments per wave ----
        const bf16x8* Asg = (const bf16x8*)As;
        const bf16x8* Bsg = diag ? (const bf16x8*)As : (const bf16x8*)Bs;
        f32x4 acc[4][8] = {};
#pragma unroll
        for (int s = 0; s < 4; ++s) {
            int g = s * 4 + kb;
            bf16x8 aF[4], bF[8];
#pragma unroll
            for (int fr = 0; fr < 4; ++fr) {
                int R = wr * 64 + fr * 16 + low;
                aF[fr] = Asg[R * 16 + (g ^ low)];
            }
#pragma unroll
            for (int fc = 0; fc < 8; ++fc) {
                int C = wc * 128 + fc * 16 + low;
                bF[fc] = Bsg[C * 16 + (g ^ low)];
            }
#pragma unroll
            for (int fr = 0; fr < 4; ++fr)
#pragma unroll
                for (int fc = 0; fc < 8; ++fc)
                    acc[fr][fc] = __builtin_amdgcn_mfma_f32_16x16x32_bf16(
                        aF[fr], bF[fc], acc[fr][fc], 0, 0, 0);
        }
        __syncthreads();   // all waves done reading As/Bs; safe to overwrite

        // ---- issue NEXT tile's staging now; epilogue hides the latency ----
        int nti = ti, ntj = tj + 1;
        if (ntj == NT) { ++nti; ntj = nti; }
        if (n + 1 < cnt) {
            if (nti != ti)  stage(Fbf + (size_t)nti * TILE * KDIM, As);
            if (nti != ntj) stage(Fbf + (size_t)ntj * TILE * KDIM, Bs);
        }

        // ---- epilogue: Cauchy + row/col partial sums (pure VALU) ----
        // C/D layout: col = low, row = kb*4 + reg (within each 16x16 frag)
        float sqi[4][4], sqj[8];
#pragma unroll
        for (int fr = 0; fr < 4; ++fr)
#pragma unroll
            for (int r = 0; r < 4; ++r)
                sqi[fr][r] = sq[I + wr * 64 + fr * 16 + kb * 4 + r];
#pragma unroll
        for (int fc = 0; fc < 8; ++fc)
            sqj[fc] = sq[J + wc * 128 + fc * 16 + low];

        float rowPart[4][4] = {};
        float colPart[8] = {};
#pragma unroll
        for (int fr = 0; fr < 4; ++fr) {
#pragma unroll
            for (int fc = 0; fc < 8; ++fc) {
#pragma unroll
                for (int r = 0; r < 4; ++r) {
                    float d2 = sqi[fr][r] + sqj[fc] - 2.0f * acc[fr][fc][r];
                    d2 = fmaxf(d2, 0.0f);
                    float v = __builtin_amdgcn_rcpf(1.0f + d2);
                    rowPart[fr][r] += v;
                    colPart[fc] += v;
                }
            }
        }

        // row partials: reduce across the 16 lanes sharing a row (low)
#pragma unroll
        for (int fr = 0; fr < 4; ++fr)
#pragma unroll
            for (int r = 0; r < 4; ++r) {
                float x = rowPart[fr][r];
                x += __shfl_xor(x, 1);
                x += __shfl_xor(x, 2);
                x += __shfl_xor(x, 4);
                x += __shfl_xor(x, 8);
                if (low == 0)
                    rowAcc[wr * 64 + fr * 16 + kb * 4 + r][wc] = x;
            }

        // col partials: reduce across the 4 lane-quads (kb)
#pragma unroll
        for (int fc = 0; fc < 8; ++fc) {
            float x = colPart[fc];
            x += __shfl_xor(x, 16);
            x += __shfl_xor(x, 32);
            if (kb == 0)
                colAcc[wc * 128 + fc * 16 + low][wr] = x;
        }
        __syncthreads();   // rowAcc/colAcc ready; next-tile staging drained

        // deterministic scatter (no atomics): slot tj holds row-contribs of
        // panel ti; slot ti holds col-contribs of panel tj. For any element
        // in tile-row r: slots {r..31} from rows, {0..r-1} from cols — each
        // of the 32 slots written exactly once. No init needed.
        if (t < TILE) {
            Tpart[tj * N_TOTAL + I + t] = rowAcc[t][0] + rowAcc[t][1];
        } else if (!diag) {
            int c = t - TILE;
            Tpart[ti * N_TOTAL + J + c] =
                colAcc[c][0] + colAcc[c][1] + colAcc[c][2] + colAcc[c][3];
        }

        ti = nti; tj = ntj;
    }
}

// ---------------------------------------------------------------------------
// Kernel C: neg term. 32 blocks x 256 threads; thread i column-reduces the
// 32 Tpart slots (coalesced, L2-resident), log(T-1); lanes <32 fold the pos
// partials; block-reduce; one atomicAdd into out per block (32 total).
// ---------------------------------------------------------------------------
__global__ __launch_bounds__(256) void k_final(const float* __restrict__ Tpart,
                                               const float* __restrict__ posPart,
                                               float* __restrict__ out) {
    int t = threadIdx.x;
    int i = blockIdx.x * 256 + t;
    float s = 0.0f;
#pragma unroll 8
    for (int k = 0; k < NSLOT; ++k) s += Tpart[k * N_TOTAL + i];
    float v = logf(s - 1.0f);
    if (t < 32) v += 2.0f * posPart[blockIdx.x * 32 + t];  // *2 cancels /(2b)
#pragma unroll
    for (int off = 32; off > 0; off >>= 1) v += __shfl_down(v, off);
    __shared__ float red[4];
    int w = t >> 6, l = t & 63;
    if (l == 0) red[w] = v;
    __syncthreads();
    if (t == 0) {
        float S = red[0] + red[1] + red[2] + red[3];
        atomicAdd(out, S * (1.0f / (2.0f * (float)BHALF)));
    }
}

// ---------------------------------------------------------------------------
extern "C" void kernel_launch(void* const* d_in, const int* in_sizes, int n_in,
                              void* d_out, int out_size, void* d_ws, size_t ws_size,
                              hipStream_t stream) {
    const float* F = (const float*)d_in[0];
    float* out = (float*)d_out;

    char* ws = (char*)d_ws;
    __bf16* Fbf     = (__bf16*)ws;                                 // 2 MB
    float*  sq      = (float*)(ws + (size_t)N_TOTAL * KDIM * 2);   // 32 KB
    float*  posPart = sq + N_TOTAL;                                // 4 KB
    float*  Tpart   = posPart + 1024;                              // 1 MB

    k_prep_pos<<<BHALF / 4, 256, 0, stream>>>(F, Fbf, sq, posPart, out);
    k_pairwise<<<NBLK, 512, 0, stream>>>(Fbf, sq, Tpart);
    k_final<<<N_TOTAL / 256, 256, 0, stream>>>(Tpart, posPart, out);
}

// Round 6
// 97.275 us; speedup vs baseline: 1.0019x; 1.0019x over previous
//
#include <hip/hip_runtime.h>
#include <math.h>

#define N_TOTAL 8192
#define BHALF   4096
#define KDIM    128
#define NTILE   64          // 8192 / 128 tile grid
#define NCHUNK  544         // sum over ti of ceil((64-ti)/4) row-chunks
#define NSLOT   64          // Tpart slots (2 MB, same layout as proven r1)

typedef __bf16 bf16x8 __attribute__((ext_vector_type(8)));
typedef __bf16 bf16x2 __attribute__((ext_vector_type(2)));
typedef float  f32x4  __attribute__((ext_vector_type(4)));

// async global->LDS, 16B per lane; LDS dest must be lane-contiguous.
#define GLOAD_LDS16(GSRC, LDST)                                                \
    __builtin_amdgcn_global_load_lds(                                          \
        (const __attribute__((address_space(1))) void*)(GSRC),                 \
        (__attribute__((address_space(3))) void*)(LDST), 16, 0, 0)

// ---------------------------------------------------------------------------
// Kernel A (fused prep+pos): one wave per pair (i, i+BHALF).
//  - fp32 sq-norms (exact), bf16 copy, pos-pair partials to posPart,
//  - zeroes Tpart (2 floats/thread) and out[0].
// ---------------------------------------------------------------------------
__global__ __launch_bounds__(256) void k_prep_pos(const float* __restrict__ F,
                                                  __bf16* __restrict__ Fbf,
                                                  float* __restrict__ sq,
                                                  float* __restrict__ posPart,
                                                  float* __restrict__ Tpart,
                                                  float* __restrict__ out) {
    int t = threadIdx.x;
    int w = t >> 6, l = t & 63;
    int p = blockIdx.x * 4 + w;          // pair index 0..4095
    const float2* r1 = (const float2*)(F + (size_t)p * KDIM);
    const float2* r2 = (const float2*)(F + (size_t)(p + BHALF) * KDIM);
    float2 a = r1[l];
    float2 c = r2[l];

    // zero Tpart: 64*8192 floats / (1024 blk * 256 thr) = 2 per thread
    int zi = blockIdx.x * 256 + t;
    Tpart[zi] = 0.0f;
    Tpart[zi + 262144] = 0.0f;

    float s1 = fmaf(a.x, a.x, a.y * a.y);
    float s2 = fmaf(c.x, c.x, c.y * c.y);
    float dp = fmaf(a.x, c.x, a.y * c.y);
#pragma unroll
    for (int off = 32; off > 0; off >>= 1) {
        s1 += __shfl_down(s1, off);
        s2 += __shfl_down(s2, off);
        dp += __shfl_down(dp, off);
    }

    bf16x2 pa, pc;
    pa[0] = (__bf16)a.x; pa[1] = (__bf16)a.y;
    pc[0] = (__bf16)c.x; pc[1] = (__bf16)c.y;
    ((bf16x2*)(Fbf + (size_t)p * KDIM))[l] = pa;
    ((bf16x2*)(Fbf + (size_t)(p + BHALF) * KDIM))[l] = pc;

    __shared__ float posRed[4];
    if (l == 0) {
        sq[p] = s1;
        sq[p + BHALF] = s2;
        float d2 = fmaxf(s1 + s2 - 2.0f * dp, 0.0f);
        posRed[w] = logf(1.0f + d2);
    }
    __syncthreads();
    if (t == 0) {
        posPart[blockIdx.x] = posRed[0] + posRed[1] + posRed[2] + posRed[3];
        if (blockIdx.x == 0) out[0] = 0.0f;
    }
}

// ---------------------------------------------------------------------------
// Kernel B: MFMA pairwise Cauchy row/col sums, 128x128 tiles, A-IN-REGISTERS.
// Each block owns a chunk of <=4 tiles within ONE tile-row ti:
//  - A panel fragments live in registers (aR[2][4] = 32 VGPR/wave), loaded
//    from L2 once per block -> LDS stages B ONLY (32 KB single buffer).
//  - row partials accumulate in REGISTERS across the whole chunk (ti fixed);
//    row shuffle-reduce + scatter happen once per block.
//  - per tile: K-loop -> barrier1 -> stage next B -> epilogue (Cauchy +
//    col reduce) -> barrier2 -> col scatter.  (proven r1 schedule)
// Tpart slots (64, disjoint, zero-init'd): rows of panel ti -> slot ti+c;
// cols of panel tj from tile (ti,tj) -> slot ti (< tj). Diag: rows only.
// ---------------------------------------------------------------------------
__global__ __launch_bounds__(512, 4) void k_pairwise(
        const __bf16* __restrict__ Fbf,
        const float* __restrict__ sq,
        float* __restrict__ Tpart) {
    __shared__ __align__(16) __bf16 Bs[128 * KDIM];   // 32 KB
    __shared__ float colAcc[128][4];
    __shared__ float rowAcc[128][2];

    int t = threadIdx.x;
    int w = t >> 6;              // wave 0..7
    int l = t & 63;
    int wr = w >> 1, wc = w & 1; // 4x2 wave grid: 32 rows x 64 cols each
    int low = l & 15, kb = l >> 4;

    // decode bid -> (ti, c): row ti has ceil((64-ti)/4) chunks of <=4 tiles
    int bid = blockIdx.x;
    int ti = 0, base = 0;
    for (;;) {
        int nch = (NTILE - ti + 3) >> 2;
        if (bid < base + nch) break;
        base += nch;
        ++ti;
    }
    int c = bid - base;
    int tj0 = ti + c * 4;
    int cnt = NTILE - tj0; if (cnt > 4) cnt = 4;
    int I = ti * 128;

    // stage one 128x128 bf16 tile into Bs (XOR-swizzled global source)
    auto stage = [&](const __bf16* src) {
#pragma unroll
        for (int it = 0; it < 4; ++it) {
            int f = it * 512 + t;            // granule slot 0..2047
            int row = f >> 4;
            int sg = f & 15;
            int g = sg ^ (row & 15);         // global granule landing here
            GLOAD_LDS16(src + row * KDIM + g * 8, Bs + (size_t)f * 8);
        }
    };

    // ---- prologue: first B stage + A panel -> registers + sq[i] ----
    stage(Fbf + (size_t)tj0 * 128 * KDIM);
    const __bf16* baseA = Fbf + (size_t)(I + wr * 32 + low) * KDIM + kb * 8;
    bf16x8 aR[2][4];
#pragma unroll
    for (int fr = 0; fr < 2; ++fr)
#pragma unroll
        for (int s = 0; s < 4; ++s)
            aR[fr][s] = *(const bf16x8*)(baseA + fr * 16 * KDIM + s * 32);
    float sqi[2][4];
#pragma unroll
    for (int fr = 0; fr < 2; ++fr)
#pragma unroll
        for (int r = 0; r < 4; ++r)
            sqi[fr][r] = sq[I + wr * 32 + fr * 16 + kb * 4 + r];
    float rowPartR[2][4] = {};   // accumulated across ALL tiles of the chunk
    __syncthreads();             // drains aR loads + B stage

#pragma unroll 1
    for (int n = 0; n < cnt; ++n) {
        int tj = tj0 + n;
        int J = tj * 128;
        bool diag = (tj == ti);

        // ---- MFMA K-loop: 4 steps of K=32, A from regs, B from LDS ----
        const bf16x8* Bsg = (const bf16x8*)Bs;
        f32x4 acc[2][4] = {};
#pragma unroll
        for (int s = 0; s < 4; ++s) {
            int g = s * 4 + kb;
            bf16x8 bF[4];
#pragma unroll
            for (int fc = 0; fc < 4; ++fc) {
                int C = wc * 64 + fc * 16 + low;
                bF[fc] = Bsg[C * 16 + (g ^ low)];
            }
#pragma unroll
            for (int fr = 0; fr < 2; ++fr)
#pragma unroll
                for (int fc = 0; fc < 4; ++fc)
                    acc[fr][fc] = __builtin_amdgcn_mfma_f32_16x16x32_bf16(
                        aR[fr][s], bF[fc], acc[fr][fc], 0, 0, 0);
        }
        __syncthreads();   // all waves done reading Bs; safe to overwrite

        // ---- issue NEXT tile's B staging; epilogue hides the latency ----
        if (n + 1 < cnt) stage(Fbf + (size_t)(tj + 1) * 128 * KDIM);

        // ---- epilogue: Cauchy; rows -> registers, cols -> LDS ----
        // C/D layout: col = low, row = kb*4 + reg (within each 16x16 frag)
        float sqj[4];
#pragma unroll
        for (int fc = 0; fc < 4; ++fc)
            sqj[fc] = sq[J + wc * 64 + fc * 16 + low];

        float colPart[4] = {0.f, 0.f, 0.f, 0.f};
#pragma unroll
        for (int fr = 0; fr < 2; ++fr) {
#pragma unroll
            for (int fc = 0; fc < 4; ++fc) {
#pragma unroll
                for (int r = 0; r < 4; ++r) {
                    float d2 = sqi[fr][r] + sqj[fc] - 2.0f * acc[fr][fc][r];
                    d2 = fmaxf(d2, 0.0f);
                    float v = __builtin_amdgcn_rcpf(1.0f + d2);
                    rowPartR[fr][r] += v;
                    colPart[fc] += v;
                }
            }
        }

        // col partials: reduce across the 4 lane-quads (kb)
#pragma unroll
        for (int fc = 0; fc < 4; ++fc) {
            float x = colPart[fc];
            x += __shfl_xor(x, 16);
            x += __shfl_xor(x, 32);
            if (kb == 0)
                colAcc[wc * 64 + fc * 16 + low][wr] = x;
        }
        __syncthreads();   // colAcc ready; next B stage drained

        // col scatter: slot ti (< tj), unique per (tj, ti); diag skipped
        if (!diag && t < 128) {
            Tpart[ti * N_TOTAL + J + t] =
                colAcc[t][0] + colAcc[t][1] + colAcc[t][2] + colAcc[t][3];
        }
    }

    // ---- once per block: row reduce (16 lanes sharing a row) + scatter ----
#pragma unroll
    for (int fr = 0; fr < 2; ++fr)
#pragma unroll
        for (int r = 0; r < 4; ++r) {
            float x = rowPartR[fr][r];
            x += __shfl_xor(x, 1);
            x += __shfl_xor(x, 2);
            x += __shfl_xor(x, 4);
            x += __shfl_xor(x, 8);
            if (low == 0)
                rowAcc[wr * 32 + fr * 16 + kb * 4 + r][wc] = x;
        }
    __syncthreads();
    // row slot ti+c: rows of panel p use slots >= p, cols use < p (disjoint)
    if (t < 128) {
        Tpart[(ti + c) * N_TOTAL + I + t] = rowAcc[t][0] + rowAcc[t][1];
    }
}

// ---------------------------------------------------------------------------
// Kernel C: neg term. 32 blocks x 256 threads; thread i column-reduces the
// 64 Tpart slots (coalesced, L2-resident), log(T-1); lanes <32 fold the pos
// partials; block-reduce; one atomicAdd into out per block (32 total).
// ---------------------------------------------------------------------------
__global__ __launch_bounds__(256) void k_final(const float* __restrict__ Tpart,
                                               const float* __restrict__ posPart,
                                               float* __restrict__ out) {
    int t = threadIdx.x;
    int i = blockIdx.x * 256 + t;
    float s = 0.0f;
#pragma unroll 8
    for (int k = 0; k < NSLOT; ++k) s += Tpart[k * N_TOTAL + i];
    float v = logf(s - 1.0f);
    if (t < 32) v += 2.0f * posPart[blockIdx.x * 32 + t];  // *2 cancels /(2b)
#pragma unroll
    for (int off = 32; off > 0; off >>= 1) v += __shfl_down(v, off);
    __shared__ float red[4];
    int w = t >> 6, l = t & 63;
    if (l == 0) red[w] = v;
    __syncthreads();
    if (t == 0) {
        float S = red[0] + red[1] + red[2] + red[3];
        atomicAdd(out, S * (1.0f / (2.0f * (float)BHALF)));
    }
}

// ---------------------------------------------------------------------------
extern "C" void kernel_launch(void* const* d_in, const int* in_sizes, int n_in,
                              void* d_out, int out_size, void* d_ws, size_t ws_size,
                              hipStream_t stream) {
    const float* F = (const float*)d_in[0];
    float* out = (float*)d_out;

    char* ws = (char*)d_ws;
    __bf16* Fbf     = (__bf16*)ws;                                 // 2 MB
    float*  sq      = (float*)(ws + (size_t)N_TOTAL * KDIM * 2);   // 32 KB
    float*  posPart = sq + N_TOTAL;                                // 4 KB
    float*  Tpart   = posPart + 1024;                              // 2 MB

    k_prep_pos<<<BHALF / 4, 256, 0, stream>>>(F, Fbf, sq, posPart, Tpart, out);
    k_pairwise<<<NCHUNK, 512, 0, stream>>>(Fbf, sq, Tpart);
    k_final<<<N_TOTAL / 256, 256, 0, stream>>>(Tpart, posPart, out);
}

// Round 7
// 85.374 us; speedup vs baseline: 1.1415x; 1.1394x over previous
//
#include <hip/hip_runtime.h>
#include <math.h>

#define N_TOTAL 8192
#define BHALF   4096
#define KDIM    128
#define NTILE   64          // 8192 / 128 tile grid
#define NTRI    2080        // 64*65/2 triangular tiles
#define NBLK_PW 512         // persistent blocks, exactly 2 per CU

typedef __bf16 bf16x8 __attribute__((ext_vector_type(8)));
typedef __bf16 bf16x2 __attribute__((ext_vector_type(2)));
typedef float  f32x4  __attribute__((ext_vector_type(4)));

// async global->LDS, 16B per lane; LDS dest must be lane-contiguous.
#define GLOAD_LDS16(GSRC, LDST)                                                \
    __builtin_amdgcn_global_load_lds(                                          \
        (const __attribute__((address_space(1))) void*)(GSRC),                 \
        (__attribute__((address_space(3))) void*)(LDST), 16, 0, 0)

// ---------------------------------------------------------------------------
// Kernel A (fused prep+pos): one wave per pair (i, i+BHALF).
//  - fp32 sq-norms for both rows (exact), bf16 copy of both rows,
//  - positive-pair term written to posPart[block] (no atomics),
//  - block 0 zeroes out[0] (replaces the hipMemsetAsync dispatch).
// ---------------------------------------------------------------------------
__global__ __launch_bounds__(256) void k_prep_pos(const float* __restrict__ F,
                                                  __bf16* __restrict__ Fbf,
                                                  float* __restrict__ sq,
                                                  float* __restrict__ posPart,
                                                  float* __restrict__ out) {
    int t = threadIdx.x;
    int w = t >> 6, l = t & 63;
    int p = blockIdx.x * 4 + w;          // pair index 0..4095
    const float2* r1 = (const float2*)(F + (size_t)p * KDIM);
    const float2* r2 = (const float2*)(F + (size_t)(p + BHALF) * KDIM);
    float2 a = r1[l];
    float2 c = r2[l];

    float s1 = fmaf(a.x, a.x, a.y * a.y);
    float s2 = fmaf(c.x, c.x, c.y * c.y);
    float dp = fmaf(a.x, c.x, a.y * c.y);
#pragma unroll
    for (int off = 32; off > 0; off >>= 1) {
        s1 += __shfl_down(s1, off);
        s2 += __shfl_down(s2, off);
        dp += __shfl_down(dp, off);
    }

    bf16x2 pa, pc;
    pa[0] = (__bf16)a.x; pa[1] = (__bf16)a.y;
    pc[0] = (__bf16)c.x; pc[1] = (__bf16)c.y;
    ((bf16x2*)(Fbf + (size_t)p * KDIM))[l] = pa;
    ((bf16x2*)(Fbf + (size_t)(p + BHALF) * KDIM))[l] = pc;

    __shared__ float posRed[4];
    if (l == 0) {
        sq[p] = s1;
        sq[p + BHALF] = s2;
        float d2 = fmaxf(s1 + s2 - 2.0f * dp, 0.0f);
        posRed[w] = logf(1.0f + d2);
    }
    __syncthreads();
    if (t == 0) {
        posPart[blockIdx.x] = posRed[0] + posRed[1] + posRed[2] + posRed[3];
        if (blockIdx.x == 0) out[0] = 0.0f;
    }
}

// ---------------------------------------------------------------------------
// Kernel B: MFMA pairwise Cauchy row/col sums, 128x128 tiles.
// 512 persistent blocks; block b owns a CONTIGUOUS chunk of 4-5 triangular
// tiles (row-major in (ti,tj)). A panel is re-staged only when ti changes;
// diagonal tiles read the B operand straight from the A panel (no B stage).
// NO atomics: tile (ti,tj) writes row sums to Tpart[tj][I..I+127] and col
// sums to Tpart[ti][J..J+127] — each (slot, element) written exactly once.
// 16-B-granule XOR swizzle on the GLOBAL side of global_load_lds keeps the
// fragment ds_read_b128s conflict-free (2-way max = free).
// ---------------------------------------------------------------------------
__global__ __launch_bounds__(512, 4) void k_pairwise(
        const __bf16* __restrict__ Fbf,
        const float* __restrict__ sq,
        float* __restrict__ Tpart) {
    __shared__ __align__(16) __bf16 As[128 * 128];
    __shared__ __align__(16) __bf16 Bs[128 * 128];
    __shared__ float rowAcc[128][2];
    __shared__ float colAcc[128][4];

    int t = threadIdx.x;
    int w = t >> 6;              // wave 0..7
    int l = t & 63;
    int wr = w >> 1, wc = w & 1; // 4x2 wave grid
    int low = l & 15, kb = l >> 4;

    // contiguous chunk: blocks 0..31 own 5 tiles, rest own 4 (32*5+480*4=2080)
    int bid = blockIdx.x;
    int start = bid * 4 + (bid < 32 ? bid : 32);
    int cnt = (bid < 32) ? 5 : 4;

    // decode start -> (ti, tj) on the 64x64 upper triangle
    int ti = (int)floorf((129.0f - sqrtf(16641.0f - 8.0f * (float)start)) * 0.5f);
    while (ti * (129 - ti) / 2 > start) --ti;
    while ((ti + 1) * (128 - ti) / 2 <= start) ++ti;
    int tj = ti + (start - ti * (129 - ti) / 2);

    // stage one 128x128 bf16 tile (2048 16B granules, XOR-swizzled source)
    auto stage = [&](const __bf16* src, __bf16* dst) {
#pragma unroll
        for (int it = 0; it < 4; ++it) {
            int f = it * 512 + t;            // granule slot 0..2047
            int row = f >> 4;
            int sg = f & 15;
            int g = sg ^ (row & 15);         // global granule landing here
            GLOAD_LDS16(src + row * KDIM + g * 8, dst + (size_t)f * 8);
        }
    };

    int curTi = -1;
#pragma unroll 1
    for (int n = 0; n < cnt; ++n) {
        int I = ti * 128, J = tj * 128;
        bool diag = (ti == tj);

        // ---- stage tiles; skip A if panel unchanged ----
        if (ti != curTi) {
            stage(Fbf + (size_t)I * KDIM, As);
            curTi = ti;
        }
        if (!diag) {
            stage(Fbf + (size_t)J * KDIM, Bs);
        }
        __syncthreads();

        // ---- MFMA K-loop: 4 steps of K=32, 2x4 fragments per wave ----
        const bf16x8* Asg = (const bf16x8*)As;
        const bf16x8* Bsg = diag ? (const bf16x8*)As : (const bf16x8*)Bs;
        f32x4 acc[2][4] = {};
#pragma unroll
        for (int s = 0; s < 4; ++s) {
            int g = s * 4 + kb;
            bf16x8 aF[2], bF[4];
#pragma unroll
            for (int fr = 0; fr < 2; ++fr) {
                int R = wr * 32 + fr * 16 + low;
                aF[fr] = Asg[R * 16 + (g ^ low)];
            }
#pragma unroll
            for (int fc = 0; fc < 4; ++fc) {
                int C = wc * 64 + fc * 16 + low;
                bF[fc] = Bsg[C * 16 + (g ^ low)];
            }
#pragma unroll
            for (int fr = 0; fr < 2; ++fr)
#pragma unroll
                for (int fc = 0; fc < 4; ++fc)
                    acc[fr][fc] = __builtin_amdgcn_mfma_f32_16x16x32_bf16(
                        aF[fr], bF[fc], acc[fr][fc], 0, 0, 0);
        }

        // ---- epilogue: Cauchy + row/col partial sums ----
        // C/D layout: col = low, row = kb*4 + reg (within each 16x16 frag)
        float sqi[2][4], sqj[4];
#pragma unroll
        for (int fr = 0; fr < 2; ++fr)
#pragma unroll
            for (int r = 0; r < 4; ++r)
                sqi[fr][r] = sq[I + wr * 32 + fr * 16 + kb * 4 + r];
#pragma unroll
        for (int fc = 0; fc < 4; ++fc)
            sqj[fc] = sq[J + wc * 64 + fc * 16 + low];

        float rowPart[2][4] = {};
        float colPart[4] = {0.f, 0.f, 0.f, 0.f};
#pragma unroll
        for (int fr = 0; fr < 2; ++fr) {
#pragma unroll
            for (int fc = 0; fc < 4; ++fc) {
#pragma unroll
                for (int r = 0; r < 4; ++r) {
                    float d2 = sqi[fr][r] + sqj[fc] - 2.0f * acc[fr][fc][r];
                    d2 = fmaxf(d2, 0.0f);
                    float v = __builtin_amdgcn_rcpf(1.0f + d2);
                    rowPart[fr][r] += v;
                    colPart[fc] += v;
                }
            }
        }

        // row partials: reduce across the 16 lanes sharing a row (low)
#pragma unroll
        for (int fr = 0; fr < 2; ++fr)
#pragma unroll
            for (int r = 0; r < 4; ++r) {
                float x = rowPart[fr][r];
                x += __shfl_xor(x, 1);
                x += __shfl_xor(x, 2);
                x += __shfl_xor(x, 4);
                x += __shfl_xor(x, 8);
                if (low == 0)
                    rowAcc[wr * 32 + fr * 16 + kb * 4 + r][wc] = x;
            }

        // col partials: reduce across the 4 lane-quads (kb)
#pragma unroll
        for (int fc = 0; fc < 4; ++fc) {
            float x = colPart[fc];
            x += __shfl_xor(x, 16);
            x += __shfl_xor(x, 32);
            if (kb == 0)
                colAcc[wc * 64 + fc * 16 + low][wr] = x;
        }
        __syncthreads();

        // deterministic scatter instead of atomics:
        // slot tj holds row-contribs of panel ti; slot ti holds col-contribs
        // of panel tj. For any element, slots 0..63 are each written once.
        if (t < 128) {
            Tpart[tj * N_TOTAL + I + t] = rowAcc[t][0] + rowAcc[t][1];
        } else if (t < 256 && !diag) {
            int c = t - 128;
            Tpart[ti * N_TOTAL + J + c] =
                colAcc[c][0] + colAcc[c][1] + colAcc[c][2] + colAcc[c][3];
        }

        // advance to next triangular tile
        ++tj;
        if (tj == NTILE) { ++ti; tj = ti; }
    }
}

// ---------------------------------------------------------------------------
// Kernel C: neg term. 32 blocks x 256 threads; thread i column-reduces the
// 64 Tpart slots (fully coalesced), takes log(T-1); lanes <32 also fold the
// pos partials; block-reduce; one atomicAdd into out per block (32 total).
// ---------------------------------------------------------------------------
__global__ __launch_bounds__(256) void k_final(const float* __restrict__ Tpart,
                                               const float* __restrict__ posPart,
                                               float* __restrict__ out) {
    int t = threadIdx.x;
    int i = blockIdx.x * 256 + t;
    float s = 0.0f;
#pragma unroll 8
    for (int k = 0; k < NTILE; ++k) s += Tpart[k * N_TOTAL + i];
    float v = logf(s - 1.0f);
    if (t < 32) v += 2.0f * posPart[blockIdx.x * 32 + t];  // *2 cancels /(2b)
#pragma unroll
    for (int off = 32; off > 0; off >>= 1) v += __shfl_down(v, off);
    __shared__ float red[4];
    int w = t >> 6, l = t & 63;
    if (l == 0) red[w] = v;
    __syncthreads();
    if (t == 0) {
        float S = red[0] + red[1] + red[2] + red[3];
        atomicAdd(out, S * (1.0f / (2.0f * (float)BHALF)));
    }
}

// ---------------------------------------------------------------------------
extern "C" void kernel_launch(void* const* d_in, const int* in_sizes, int n_in,
                              void* d_out, int out_size, void* d_ws, size_t ws_size,
                              hipStream_t stream) {
    const float* F = (const float*)d_in[0];
    float* out = (float*)d_out;

    char* ws = (char*)d_ws;
    __bf16* Fbf     = (__bf16*)ws;                                 // 2 MB
    float*  sq      = (float*)(ws + (size_t)N_TOTAL * KDIM * 2);   // 32 KB
    float*  posPart = sq + N_TOTAL;                                // 4 KB
    float*  Tpart   = posPart + 1024;                              // 2 MB

    k_prep_pos<<<BHALF / 4, 256, 0, stream>>>(F, Fbf, sq, posPart, out);
    k_pairwise<<<NBLK_PW, 512, 0, stream>>>(Fbf, sq, Tpart);
    k_final<<<N_TOTAL / 256, 256, 0, stream>>>(Tpart, posPart, out);
}

// Round 8
// 82.239 us; speedup vs baseline: 1.1850x; 1.0381x over previous
//
#include <hip/hip_runtime.h>
#include <math.h>

#define N_TOTAL 8192
#define BHALF   4096
#define KDIM    128
#define NTILE   64          // 8192 / 128 tile grid
#define NTRI    2080        // 64*65/2 triangular tiles
#define NBLK_PW 512         // persistent blocks, exactly 2 per CU

typedef __bf16 bf16x8 __attribute__((ext_vector_type(8)));
typedef __bf16 bf16x2 __attribute__((ext_vector_type(2)));
typedef float  f32x4  __attribute__((ext_vector_type(4)));

// async global->LDS, 16B per lane; LDS dest must be lane-contiguous.
#define GLOAD_LDS16(GSRC, LDST)                                                \
    __builtin_amdgcn_global_load_lds(                                          \
        (const __attribute__((address_space(1))) void*)(GSRC),                 \
        (__attribute__((address_space(3))) void*)(LDST), 16, 0, 0)

// butterfly-add via DPP (VALU pipe, not DS): x += lane-permuted x.
// 0xB1 = quad_perm(1,0,3,2) -> xor1 ; 0x4E = quad_perm(2,3,0,1) -> xor2 ;
// 0x141 = row_half_mirror -> xor-within-8 ; 0x140 = row_mirror -> xor-within-16.
template <int CTRL>
__device__ __forceinline__ float dpp_add(float x) {
    union { float f; int i; } u, v;
    u.f = x;
    v.i = __builtin_amdgcn_update_dpp(0, u.i, CTRL, 0xF, 0xF, true);
    return x + v.f;
}

// ---------------------------------------------------------------------------
// Kernel A (fused prep+pos): one wave per pair (i, i+BHALF).
//  - fp32 sq-norms for both rows (exact), bf16 copy of both rows,
//  - positive-pair term written to posPart[block] (no atomics),
//  - block 0 zeroes out[0].
// ---------------------------------------------------------------------------
__global__ __launch_bounds__(256) void k_prep_pos(const float* __restrict__ F,
                                                  __bf16* __restrict__ Fbf,
                                                  float* __restrict__ sq,
                                                  float* __restrict__ posPart,
                                                  float* __restrict__ out) {
    int t = threadIdx.x;
    int w = t >> 6, l = t & 63;
    int p = blockIdx.x * 4 + w;          // pair index 0..4095
    const float2* r1 = (const float2*)(F + (size_t)p * KDIM);
    const float2* r2 = (const float2*)(F + (size_t)(p + BHALF) * KDIM);
    float2 a = r1[l];
    float2 c = r2[l];

    float s1 = fmaf(a.x, a.x, a.y * a.y);
    float s2 = fmaf(c.x, c.x, c.y * c.y);
    float dp = fmaf(a.x, c.x, a.y * c.y);
#pragma unroll
    for (int off = 32; off > 0; off >>= 1) {
        s1 += __shfl_down(s1, off);
        s2 += __shfl_down(s2, off);
        dp += __shfl_down(dp, off);
    }

    bf16x2 pa, pc;
    pa[0] = (__bf16)a.x; pa[1] = (__bf16)a.y;
    pc[0] = (__bf16)c.x; pc[1] = (__bf16)c.y;
    ((bf16x2*)(Fbf + (size_t)p * KDIM))[l] = pa;
    ((bf16x2*)(Fbf + (size_t)(p + BHALF) * KDIM))[l] = pc;

    __shared__ float posRed[4];
    if (l == 0) {
        sq[p] = s1;
        sq[p + BHALF] = s2;
        float d2 = fmaxf(s1 + s2 - 2.0f * dp, 0.0f);
        posRed[w] = logf(1.0f + d2);
    }
    __syncthreads();
    if (t == 0) {
        posPart[blockIdx.x] = posRed[0] + posRed[1] + posRed[2] + posRed[3];
        if (blockIdx.x == 0) out[0] = 0.0f;
    }
}

// ---------------------------------------------------------------------------
// Kernel B: MFMA pairwise Cauchy row/col sums, 128x128 tiles.
// 512 persistent blocks; block b owns a CONTIGUOUS chunk of 4-5 triangular
// tiles (row-major in (ti,tj)). A panel is re-staged only when ti changes;
// diagonal tiles read the B operand straight from the A panel (no B stage).
// NO atomics: tile (ti,tj) writes row sums to Tpart[tj][I..I+127] and col
// sums to Tpart[ti][J..J+127] — each (slot, element) written exactly once.
// Row-sum 16-lane butterfly runs on DPP (VALU) instead of ds_bpermute,
// keeping the DS pipe free for ds_read_b128 + staging writes.
// ---------------------------------------------------------------------------
__global__ __launch_bounds__(512, 4) void k_pairwise(
        const __bf16* __restrict__ Fbf,
        const float* __restrict__ sq,
        float* __restrict__ Tpart) {
    __shared__ __align__(16) __bf16 As[128 * 128];
    __shared__ __align__(16) __bf16 Bs[128 * 128];
    __shared__ float rowAcc[128][2];
    __shared__ float colAcc[128][4];

    int t = threadIdx.x;
    int w = t >> 6;              // wave 0..7
    int l = t & 63;
    int wr = w >> 1, wc = w & 1; // 4x2 wave grid
    int low = l & 15, kb = l >> 4;

    // contiguous chunk: blocks 0..31 own 5 tiles, rest own 4 (32*5+480*4=2080)
    int bid = blockIdx.x;
    int start = bid * 4 + (bid < 32 ? bid : 32);
    int cnt = (bid < 32) ? 5 : 4;

    // decode start -> (ti, tj) on the 64x64 upper triangle
    int ti = (int)floorf((129.0f - sqrtf(16641.0f - 8.0f * (float)start)) * 0.5f);
    while (ti * (129 - ti) / 2 > start) --ti;
    while ((ti + 1) * (128 - ti) / 2 <= start) ++ti;
    int tj = ti + (start - ti * (129 - ti) / 2);

    // stage one 128x128 bf16 tile (2048 16B granules, XOR-swizzled source)
    auto stage = [&](const __bf16* src, __bf16* dst) {
#pragma unroll
        for (int it = 0; it < 4; ++it) {
            int f = it * 512 + t;            // granule slot 0..2047
            int row = f >> 4;
            int sg = f & 15;
            int g = sg ^ (row & 15);         // global granule landing here
            GLOAD_LDS16(src + row * KDIM + g * 8, dst + (size_t)f * 8);
        }
    };

    int curTi = -1;
#pragma unroll 1
    for (int n = 0; n < cnt; ++n) {
        int I = ti * 128, J = tj * 128;
        bool diag = (ti == tj);

        // ---- stage tiles; skip A if panel unchanged ----
        if (ti != curTi) {
            stage(Fbf + (size_t)I * KDIM, As);
            curTi = ti;
        }
        if (!diag) {
            stage(Fbf + (size_t)J * KDIM, Bs);
        }
        __syncthreads();

        // ---- MFMA K-loop: 4 steps of K=32, 2x4 fragments per wave ----
        const bf16x8* Asg = (const bf16x8*)As;
        const bf16x8* Bsg = diag ? (const bf16x8*)As : (const bf16x8*)Bs;
        f32x4 acc[2][4] = {};
#pragma unroll
        for (int s = 0; s < 4; ++s) {
            int g = s * 4 + kb;
            bf16x8 aF[2], bF[4];
#pragma unroll
            for (int fr = 0; fr < 2; ++fr) {
                int R = wr * 32 + fr * 16 + low;
                aF[fr] = Asg[R * 16 + (g ^ low)];
            }
#pragma unroll
            for (int fc = 0; fc < 4; ++fc) {
                int C = wc * 64 + fc * 16 + low;
                bF[fc] = Bsg[C * 16 + (g ^ low)];
            }
#pragma unroll
            for (int fr = 0; fr < 2; ++fr)
#pragma unroll
                for (int fc = 0; fc < 4; ++fc)
                    acc[fr][fc] = __builtin_amdgcn_mfma_f32_16x16x32_bf16(
                        aF[fr], bF[fc], acc[fr][fc], 0, 0, 0);
        }

        // ---- epilogue: Cauchy + row/col partial sums ----
        // C/D layout: col = low, row = kb*4 + reg (within each 16x16 frag)
        // 1/(1 + max(d2,0)) = 1/max((1+sqi)+sqj-2acc, 1)  -> fold the +1.
        float sqi1[2][4], sqj[4];
#pragma unroll
        for (int fr = 0; fr < 2; ++fr)
#pragma unroll
            for (int r = 0; r < 4; ++r)
                sqi1[fr][r] = 1.0f + sq[I + wr * 32 + fr * 16 + kb * 4 + r];
#pragma unroll
        for (int fc = 0; fc < 4; ++fc)
            sqj[fc] = sq[J + wc * 64 + fc * 16 + low];

        f32x4 rowPart[2] = {};
        float colPart[4] = {0.f, 0.f, 0.f, 0.f};
#pragma unroll
        for (int fr = 0; fr < 2; ++fr) {
#pragma unroll
            for (int fc = 0; fc < 4; ++fc) {
                f32x4 vv;
#pragma unroll
                for (int r = 0; r < 4; ++r) {
                    float d2 = fmaf(acc[fr][fc][r], -2.0f,
                                    sqi1[fr][r] + sqj[fc]);
                    vv[r] = __builtin_amdgcn_rcpf(fmaxf(d2, 1.0f));
                }
                rowPart[fr] += vv;               // v_pk_add_f32 pairs
                colPart[fc] += (vv[0] + vv[1]) + (vv[2] + vv[3]);
            }
        }

        // row partials: 16-lane butterfly on the VALU via DPP (no DS ops)
#pragma unroll
        for (int fr = 0; fr < 2; ++fr)
#pragma unroll
            for (int r = 0; r < 4; ++r) {
                float x = rowPart[fr][r];
                x = dpp_add<0xB1>(x);    // xor 1 (quad_perm 1,0,3,2)
                x = dpp_add<0x4E>(x);    // xor 2 (quad_perm 2,3,0,1)
                x = dpp_add<0x141>(x);   // xor 4 (row_half_mirror)
                x = dpp_add<0x140>(x);   // xor 8 (row_mirror)
                if (low == 0)
                    rowAcc[wr * 32 + fr * 16 + kb * 4 + r][wc] = x;
            }

        // col partials: reduce across the 4 lane-quads (kb)
#pragma unroll
        for (int fc = 0; fc < 4; ++fc) {
            float x = colPart[fc];
            x += __shfl_xor(x, 16);
            x += __shfl_xor(x, 32);
            if (kb == 0)
                colAcc[wc * 64 + fc * 16 + low][wr] = x;
        }
        __syncthreads();

        // deterministic scatter instead of atomics:
        // slot tj holds row-contribs of panel ti; slot ti holds col-contribs
        // of panel tj. For any element, slots 0..63 are each written once.
        if (t < 128) {
            Tpart[tj * N_TOTAL + I + t] = rowAcc[t][0] + rowAcc[t][1];
        } else if (t < 256 && !diag) {
            int c = t - 128;
            Tpart[ti * N_TOTAL + J + c] =
                colAcc[c][0] + colAcc[c][1] + colAcc[c][2] + colAcc[c][3];
        }

        // advance to next triangular tile
        ++tj;
        if (tj == NTILE) { ++ti; tj = ti; }
    }
}

// ---------------------------------------------------------------------------
// Kernel C: neg term. 32 blocks x 256 threads; thread i column-reduces the
// 64 Tpart slots (fully coalesced), takes log(T-1); lanes <32 also fold the
// pos partials; block-reduce; one atomicAdd into out per block (32 total).
// ---------------------------------------------------------------------------
__global__ __launch_bounds__(256) void k_final(const float* __restrict__ Tpart,
                                               const float* __restrict__ posPart,
                                               float* __restrict__ out) {
    int t = threadIdx.x;
    int i = blockIdx.x * 256 + t;
    float s = 0.0f;
#pragma unroll 8
    for (int k = 0; k < NTILE; ++k) s += Tpart[k * N_TOTAL + i];
    float v = logf(s - 1.0f);
    if (t < 32) v += 2.0f * posPart[blockIdx.x * 32 + t];  // *2 cancels /(2b)
#pragma unroll
    for (int off = 32; off > 0; off >>= 1) v += __shfl_down(v, off);
    __shared__ float red[4];
    int w = t >> 6, l = t & 63;
    if (l == 0) red[w] = v;
    __syncthreads();
    if (t == 0) {
        float S = red[0] + red[1] + red[2] + red[3];
        atomicAdd(out, S * (1.0f / (2.0f * (float)BHALF)));
    }
}

// ---------------------------------------------------------------------------
extern "C" void kernel_launch(void* const* d_in, const int* in_sizes, int n_in,
                              void* d_out, int out_size, void* d_ws, size_t ws_size,
                              hipStream_t stream) {
    const float* F = (const float*)d_in[0];
    float* out = (float*)d_out;

    char* ws = (char*)d_ws;
    __bf16* Fbf     = (__bf16*)ws;                                 // 2 MB
    float*  sq      = (float*)(ws + (size_t)N_TOTAL * KDIM * 2);   // 32 KB
    float*  posPart = sq + N_TOTAL;                                // 4 KB
    float*  Tpart   = posPart + 1024;                              // 2 MB

    k_prep_pos<<<BHALF / 4, 256, 0, stream>>>(F, Fbf, sq, posPart, out);
    k_pairwise<<<NBLK_PW, 512, 0, stream>>>(Fbf, sq, Tpart);
    k_final<<<N_TOTAL / 256, 256, 0, stream>>>(Tpart, posPart, out);
}